// Round 5
// baseline (530.736 us; speedup 1.0000x reference)
//
#include <hip/hip_runtime.h>
#include <hip/hip_bf16.h>
#include <stdint.h>

// MultiHeadAttention fused forward, MI355X gfx950.
// B=4 T=1024 D=1024 H=16 HS=64.  All math bf16-MFMA with fp32 accum.

using f32x4 = __attribute__((ext_vector_type(4))) float;
using s16x8 = __attribute__((ext_vector_type(8))) short;   // 8 bf16 = 4 VGPR

#define GLOAD_LDS16(g, l)                                                          \
  __builtin_amdgcn_global_load_lds((const __attribute__((address_space(1))) void*)(g), \
                                   (__attribute__((address_space(3))) void*)(l), 16, 0, 0)

__device__ __forceinline__ unsigned short f2bf(float f) {
  unsigned u = __float_as_uint(f);
  u = (u + 0x7FFFu + ((u >> 16) & 1u)) >> 16;   // RNE, matches __float2bfloat16 for normals
  return (unsigned short)u;
}

// ---------------------------------------------------------------------------
// prep: x -> bf16; pack Wk/Wq/Wv transposed into Wt[3072][1024] bf16 (B^T layout);
// Wp -> Wpt[1024][1024] bf16 transposed; biases -> bqkv[3072] f32.
// ---------------------------------------------------------------------------
__global__ void prep_kernel(const float* __restrict__ x,
                            const float* __restrict__ Wk, const float* __restrict__ Wq,
                            const float* __restrict__ Wv,
                            const float* __restrict__ bk, const float* __restrict__ bq,
                            const float* __restrict__ bv,
                            const float* __restrict__ Wp,
                            unsigned short* __restrict__ xb,
                            unsigned short* __restrict__ Wt,
                            unsigned short* __restrict__ Wpt,
                            float* __restrict__ bqkv) {
  const int NX4 = 1048576;            // x as float4 units (4096*1024/4)
  const int NW  = 3145728;            // Wt elements (3072*1024)
  const int NWP = 1048576;            // Wpt elements
  const int NB  = 3072;
  const int total = NX4 + NW + NWP + NB;
  for (int i = blockIdx.x * blockDim.x + threadIdx.x; i < total;
       i += gridDim.x * blockDim.x) {
    if (i < NX4) {
      float4 v = ((const float4*)x)[i];
      ushort4 o;
      o.x = f2bf(v.x); o.y = f2bf(v.y); o.z = f2bf(v.z); o.w = f2bf(v.w);
      ((ushort4*)xb)[i] = o;
    } else if (i < NX4 + NW) {
      int j = i - NX4;
      int n = j >> 10, d = j & 1023;          // Wt[n][d]
      int p = n >> 10, hc = n & 1023;
      int hh = hc >> 6, e = hc & 63;
      const float* Wsrc = (p == 0) ? Wk : (p == 1) ? Wq : Wv;
      Wt[(size_t)n * 1024 + d] = f2bf(Wsrc[((size_t)hh * 1024 + d) * 64 + e]);
    } else if (i < NX4 + NW + NWP) {
      int j = i - (NX4 + NW);
      int n = j >> 10, d = j & 1023;          // Wpt[n][d] = Wp[d][n]
      Wpt[(size_t)n * 1024 + d] = f2bf(Wp[(size_t)d * 1024 + n]);
    } else {
      int j = i - (NX4 + NW + NWP);
      int p = j >> 10, c = j & 1023;
      const float* bsrc = (p == 0) ? bk : (p == 1) ? bq : bv;
      bqkv[j] = bsrc[c];
    }
  }
}

// ---------------------------------------------------------------------------
// GEMM  C[M,N] = A[M,1024] * Bt[N,1024]^T  (both bf16, B stored transposed).
// 128x128 tile, BK=64, 4 waves (2x2 of 64x64), 16x16x32 bf16 MFMA.
// global_load_lds width-16 with pre-swizzled source (rule 21), XOR-swizzled reads.
// MODE 0: QKV epilogue (bias add, scatter to K/Q [B,H,T,64] and V^T [B,H,64,T])
// MODE 1: fp32 out = acc + bias -> fout[M][1024]
// ---------------------------------------------------------------------------
template <int MODE>
__global__ __launch_bounds__(256, 2) void gemm_bt(
    const unsigned short* __restrict__ A,
    const unsigned short* __restrict__ Bt,
    const float* __restrict__ bias,
    unsigned short* __restrict__ kbuf,
    unsigned short* __restrict__ qbuf,
    unsigned short* __restrict__ vtbuf,
    float* __restrict__ fout,
    int gridN) {
  const int K = 1024;
  __shared__ __align__(16) unsigned short As[128 * 64];
  __shared__ __align__(16) unsigned short Bs[128 * 64];

  const int bm = blockIdx.x / gridN, bn = blockIdx.x % gridN;
  const int tid = threadIdx.x, wave = tid >> 6, lane = tid & 63;
  const int wm = wave >> 1, wn = wave & 1;
  const int l15 = lane & 15, l4 = lane >> 4;
  const long arow0 = (long)bm * 128;
  const long brow0 = (long)bn * 128;

  f32x4 acc[4][4];
  const f32x4 zf4 = {0.f, 0.f, 0.f, 0.f};
#pragma unroll
  for (int i = 0; i < 4; ++i)
#pragma unroll
    for (int j = 0; j < 4; ++j) acc[i][j] = zf4;

  for (int kt = 0; kt < 16; ++kt) {
#pragma unroll
    for (int s = 0; s < 4; ++s) {
      int ob = (wave * 4 + s) * 1024;         // wave-uniform LDS byte base
      int o = ob + lane * 16;
      int r = o >> 7;                          // tile row (128B rows)
      int cb = (o & 127) ^ ((r & 7) << 4);     // inverse-swizzled source column byte
      GLOAD_LDS16(A + (arow0 + r) * K + kt * 64 + (cb >> 1), (char*)As + ob);
      GLOAD_LDS16(Bt + (brow0 + r) * K + kt * 64 + (cb >> 1), (char*)Bs + ob);
    }
    __syncthreads();   // compiler drains vmcnt before s_barrier
#pragma unroll
    for (int kk = 0; kk < 2; ++kk) {
      s16x8 af[4], bfv[4];
#pragma unroll
      for (int i = 0; i < 4; ++i) {
        int row = wm * 64 + i * 16 + l15;
        int cb = (kk * 64 + l4 * 16) ^ ((row & 7) << 4);
        af[i] = *(const s16x8*)((const char*)As + row * 128 + cb);
      }
#pragma unroll
      for (int j = 0; j < 4; ++j) {
        int row = wn * 64 + j * 16 + l15;
        int cb = (kk * 64 + l4 * 16) ^ ((row & 7) << 4);
        bfv[j] = *(const s16x8*)((const char*)Bs + row * 128 + cb);
      }
#pragma unroll
      for (int i = 0; i < 4; ++i)
#pragma unroll
        for (int j = 0; j < 4; ++j)
          acc[i][j] = __builtin_amdgcn_mfma_f32_16x16x32_bf16(af[i], bfv[j], acc[i][j], 0, 0, 0);
    }
    __syncthreads();
  }

  const int gc0 = bn * 128;
  if (MODE == 0) {
    const int p = gc0 >> 10;                   // 0:k 1:q 2:v (uniform per block)
#pragma unroll
    for (int i = 0; i < 4; ++i) {
      int mrow = (int)arow0 + wm * 64 + i * 16 + l4 * 4;
      int b = mrow >> 10;
      int t = mrow & 1023;
#pragma unroll
      for (int j = 0; j < 4; ++j) {
        int gc = gc0 + wn * 64 + j * 16 + l15;
        int hc = gc & 1023;
        int hh = hc >> 6, e = hc & 63;
        float bb = bias[gc];
#pragma unroll
        for (int r = 0; r < 4; ++r) {
          unsigned short ub = f2bf(acc[i][j][r] + bb);
          if (p == 0)
            kbuf[(((long)(b * 16 + hh)) * 1024 + (t + r)) * 64 + e] = ub;
          else if (p == 1)
            qbuf[(((long)(b * 16 + hh)) * 1024 + (t + r)) * 64 + e] = ub;
          else
            vtbuf[(((long)(b * 16 + hh)) * 64 + e) * 1024 + (t + r)] = ub;
        }
      }
    }
  } else {
#pragma unroll
    for (int i = 0; i < 4; ++i) {
      long mrow = arow0 + wm * 64 + i * 16 + l4 * 4;
#pragma unroll
      for (int j = 0; j < 4; ++j) {
        int gc = gc0 + wn * 64 + j * 16 + l15;
        float bb = bias[gc];
#pragma unroll
        for (int r = 0; r < 4; ++r) fout[(mrow + r) * 1024 + gc] = acc[i][j][r] + bb;
      }
    }
  }
}

// ---------------------------------------------------------------------------
// Fused causal attention per (b,h, 128-row t-tile).
// scores = (K Q^T)/32  (faithful to reference: k@q^T), causal s<=t, softmax over s.
// Pass 1: exp-rowsums (no max-sub needed, scores are O(0.1) std).
// Pass 2: recompute QK^T, write normalized fp32 attn (zeros above diagonal),
//         stage P->LDS bf16 (XOR swizzle) and accumulate AV.
// K-frags hoisted to registers; Q,V read from global (L2-resident, no staging).
// blockIdx.x pairing swizzle balances causal work: (0,7),(1,6),(2,5),(3,4).
// ---------------------------------------------------------------------------
__global__ __launch_bounds__(256, 2) void attn_fused(
    const unsigned short* __restrict__ Kb,
    const unsigned short* __restrict__ Qb,
    const unsigned short* __restrict__ Vt,
    float* __restrict__ attn,
    unsigned short* __restrict__ outh) {
  __shared__ __align__(16) unsigned short Ps[128 * 128];
  __shared__ float rsum[2][128];
  __shared__ float rinv[128];

  const int bh = blockIdx.y;
  const int bx = blockIdx.x;
  const int ttile = (bx & 1) ? (7 - (bx >> 1)) : (bx >> 1);  // work-pairing swizzle
  const int t0 = ttile * 128;
  const int b = bh >> 4, h = bh & 15;
  const unsigned short* Kbh = Kb + (long)bh * 65536;
  const unsigned short* Qbh = Qb + (long)bh * 65536;
  const unsigned short* Vbh = Vt + (long)bh * 65536;
  float* attn_bh = attn + (long)bh * 1048576;

  const int tid = threadIdx.x, wave = tid >> 6, lane = tid & 63;
  const int wm = wave >> 1, wn = wave & 1;
  const int l15 = lane & 15, l4 = lane >> 4;
  const f32x4 zf4 = {0.f, 0.f, 0.f, 0.f};

  // K fragments (A operand), rows t0 + wm*64 + i*16 + l15, k=e contiguous
  s16x8 kf[4][2];
#pragma unroll
  for (int i = 0; i < 4; ++i)
#pragma unroll
    for (int kk = 0; kk < 2; ++kk)
      kf[i][kk] = *(const s16x8*)(Kbh + (long)(t0 + wm * 64 + i * 16 + l15) * 64 + kk * 32 + l4 * 8);

  // ---- pass 1: per-row sum of exp ----
  float rs[4][4];
#pragma unroll
  for (int i = 0; i < 4; ++i)
#pragma unroll
    for (int r = 0; r < 4; ++r) rs[i][r] = 0.f;

  for (int st = 0; st <= ttile; ++st) {
    int s0 = st * 128;
    f32x4 acc[4][4];
#pragma unroll
    for (int i = 0; i < 4; ++i)
#pragma unroll
      for (int j = 0; j < 4; ++j) acc[i][j] = zf4;
#pragma unroll
    for (int kk = 0; kk < 2; ++kk) {
      s16x8 qf[4];
#pragma unroll
      for (int j = 0; j < 4; ++j)
        qf[j] = *(const s16x8*)(Qbh + (long)(s0 + wn * 64 + j * 16 + l15) * 64 + kk * 32 + l4 * 8);
#pragma unroll
      for (int i = 0; i < 4; ++i)
#pragma unroll
        for (int j = 0; j < 4; ++j)
          acc[i][j] = __builtin_amdgcn_mfma_f32_16x16x32_bf16(kf[i][kk], qf[j], acc[i][j], 0, 0, 0);
    }
    bool diag = (st == ttile);
#pragma unroll
    for (int i = 0; i < 4; ++i)
#pragma unroll
      for (int j = 0; j < 4; ++j)
#pragma unroll
        for (int r = 0; r < 4; ++r) {
          float sc = acc[i][j][r] * 0.03125f;
          if (diag) {
            int t = t0 + wm * 64 + i * 16 + l4 * 4 + r;
            int s = s0 + wn * 64 + j * 16 + l15;
            rs[i][r] += (s <= t) ? __expf(sc) : 0.f;
          } else {
            rs[i][r] += __expf(sc);
          }
        }
  }
  // reduce over the 16 s-lanes; cross-wave (wn) combine via LDS
#pragma unroll
  for (int i = 0; i < 4; ++i)
#pragma unroll
    for (int r = 0; r < 4; ++r) {
      float v = rs[i][r];
      v += __shfl_xor(v, 1);
      v += __shfl_xor(v, 2);
      v += __shfl_xor(v, 4);
      v += __shfl_xor(v, 8);
      if (l15 == 0) rsum[wn][wm * 64 + i * 16 + l4 * 4 + r] = v;
    }
  __syncthreads();
  if (tid < 128) rinv[tid] = 1.0f / (rsum[0][tid] + rsum[1][tid]);
  __syncthreads();

  float rinv_r[4][4];
#pragma unroll
  for (int i = 0; i < 4; ++i)
#pragma unroll
    for (int r = 0; r < 4; ++r) rinv_r[i][r] = rinv[wm * 64 + i * 16 + l4 * 4 + r];

  // ---- pass 2: attn store + AV ----
  f32x4 acc2[2][4];
#pragma unroll
  for (int i = 0; i < 2; ++i)
#pragma unroll
    for (int j = 0; j < 4; ++j) acc2[i][j] = zf4;

  for (int st = 0; st < 8; ++st) {
    int s0 = st * 128;
    if (st > ttile) {            // strictly above diagonal: exact zeros
      float4 z = make_float4(0.f, 0.f, 0.f, 0.f);
#pragma unroll
      for (int q = 0; q < 16; ++q) {
        int fi = tid + q * 256;
        int row = fi >> 5, c4 = fi & 31;
        *(float4*)(attn_bh + (long)(t0 + row) * 1024 + s0 + c4 * 4) = z;
      }
      continue;
    }
    f32x4 acc[4][4];
#pragma unroll
    for (int i = 0; i < 4; ++i)
#pragma unroll
      for (int j = 0; j < 4; ++j) acc[i][j] = zf4;
#pragma unroll
    for (int kk = 0; kk < 2; ++kk) {
      s16x8 qf[4];
#pragma unroll
      for (int j = 0; j < 4; ++j)
        qf[j] = *(const s16x8*)(Qbh + (long)(s0 + wn * 64 + j * 16 + l15) * 64 + kk * 32 + l4 * 8);
#pragma unroll
      for (int i = 0; i < 4; ++i)
#pragma unroll
        for (int j = 0; j < 4; ++j)
          acc[i][j] = __builtin_amdgcn_mfma_f32_16x16x32_bf16(kf[i][kk], qf[j], acc[i][j], 0, 0, 0);
    }
    bool diag = (st == ttile);
#pragma unroll
    for (int i = 0; i < 4; ++i) {
      int tl = wm * 64 + i * 16 + l4 * 4;
#pragma unroll
      for (int j = 0; j < 4; ++j) {
        int sl = wn * 64 + j * 16 + l15;
#pragma unroll
        for (int r = 0; r < 4; ++r) {
          int t = t0 + tl + r;
          int s = s0 + sl;
          float p = (!diag || s <= t) ? __expf(acc[i][j][r] * 0.03125f) * rinv_r[i][r] : 0.f;
          attn_bh[(long)t * 1024 + s] = p;
          int lt = tl + r;
          Ps[lt * 128 + (sl ^ ((lt & 15) << 3))] = f2bf(p);   // element swz, 16B gran
        }
      }
    }
    __syncthreads();
    // AV: wave owns 32 t-rows; P from swizzled LDS (A), V^T from global (B)
#pragma unroll
    for (int kk2 = 0; kk2 < 4; ++kk2) {
      s16x8 pf[2];
#pragma unroll
      for (int i2 = 0; i2 < 2; ++i2) {
        int lt = wave * 32 + i2 * 16 + l15;
        int ls = kk2 * 32 + l4 * 8;
        pf[i2] = *(const s16x8*)&Ps[lt * 128 + (ls ^ ((lt & 15) << 3))];
      }
      s16x8 vf[4];
#pragma unroll
      for (int j2 = 0; j2 < 4; ++j2)
        vf[j2] = *(const s16x8*)(Vbh + (long)(j2 * 16 + l15) * 1024 + s0 + kk2 * 32 + l4 * 8);
#pragma unroll
      for (int i2 = 0; i2 < 2; ++i2)
#pragma unroll
        for (int j2 = 0; j2 < 4; ++j2)
          acc2[i2][j2] = __builtin_amdgcn_mfma_f32_16x16x32_bf16(pf[i2], vf[j2], acc2[i2][j2], 0, 0, 0);
    }
    __syncthreads();
  }

  // outh[b*1024+t][h*64+e] bf16, ready as A for the final GEMM
#pragma unroll
  for (int i2 = 0; i2 < 2; ++i2)
#pragma unroll
    for (int j2 = 0; j2 < 4; ++j2)
#pragma unroll
      for (int r = 0; r < 4; ++r) {
        int t = t0 + wave * 32 + i2 * 16 + l4 * 4 + r;
        int e = j2 * 16 + l15;
        outh[(long)(b * 1024 + t) * 1024 + h * 64 + e] = f2bf(acc2[i2][j2][r]);
      }
}

// ---------------------------------------------------------------------------
extern "C" void kernel_launch(void* const* d_in, const int* in_sizes, int n_in,
                              void* d_out, int out_size, void* d_ws, size_t ws_size,
                              hipStream_t stream) {
  const float* x  = (const float*)d_in[0];
  const float* Wk = (const float*)d_in[1];
  const float* bk = (const float*)d_in[2];
  const float* Wq = (const float*)d_in[3];
  const float* bq = (const float*)d_in[4];
  const float* Wv = (const float*)d_in[5];
  const float* bv = (const float*)d_in[6];
  const float* Wp = (const float*)d_in[7];
  const float* bp = (const float*)d_in[8];

  char* ws = (char*)d_ws;
  unsigned short* xb   = (unsigned short*)(ws);              // 8,388,608 B
  unsigned short* Wt   = (unsigned short*)(ws + 8388608);    // 6,291,456 B
  unsigned short* Wpt  = (unsigned short*)(ws + 14680064);   // 2,097,152 B
  float*          bqkv = (float*)(ws + 16777216);            //    12,288 B
  unsigned short* Kbuf = (unsigned short*)(ws + 16789504);   // 8,388,608 B
  unsigned short* Qbuf = (unsigned short*)(ws + 25178112);   // 8,388,608 B
  unsigned short* Vtb  = (unsigned short*)(ws + 33566720);   // 8,388,608 B
  unsigned short* outh = (unsigned short*)(ws + 41955328);   // 8,388,608 B -> 50,343,936 total

  float* out  = (float*)d_out;
  float* attn = out + 4194304;

  prep_kernel<<<dim3(4096), dim3(256), 0, stream>>>(x, Wk, Wq, Wv, bk, bq, bv, Wp,
                                                    xb, Wt, Wpt, bqkv);
  gemm_bt<0><<<dim3(768), dim3(256), 0, stream>>>(xb, Wt, bqkv, Kbuf, Qbuf, Vtb,
                                                  (float*)nullptr, 24);
  attn_fused<<<dim3(8, 64), dim3(256), 0, stream>>>(Kbuf, Qbuf, Vtb, attn, outh);
  gemm_bt<1><<<dim3(256), dim3(256), 0, stream>>>(outh, Wpt, bp,
                                                  (unsigned short*)nullptr,
                                                  (unsigned short*)nullptr,
                                                  (unsigned short*)nullptr, out, 8);
}

// Round 9
// 513.430 us; speedup vs baseline: 1.0337x; 1.0337x over previous
//
#include <hip/hip_runtime.h>
#include <hip/hip_bf16.h>
#include <stdint.h>

// MultiHeadAttention fused forward, MI355X gfx950.
// B=4 T=1024 D=1024 H=16 HS=64.  All math bf16-MFMA with fp32 accum.

using f32x4 = __attribute__((ext_vector_type(4))) float;
using s16x8 = __attribute__((ext_vector_type(8))) short;   // 8 bf16 = 4 VGPR

#define GLOAD_LDS16(g, l)                                                          \
  __builtin_amdgcn_global_load_lds((const __attribute__((address_space(1))) void*)(g), \
                                   (__attribute__((address_space(3))) void*)(l), 16, 0, 0)

__device__ __forceinline__ unsigned short f2bf(float f) {
  unsigned u = __float_as_uint(f);
  u = (u + 0x7FFFu + ((u >> 16) & 1u)) >> 16;   // RNE, matches __float2bfloat16 for normals
  return (unsigned short)u;
}

// ---------------------------------------------------------------------------
// prep2: block-range dispatch, all transposes LDS-tiled (coalesced both sides).
//   [0,1024)    x -> bf16 (float4 loads)
//   [1024,1792) Wk/Wq/Wv [16][1024][64] -> Wt[p*1024+h*64+e][d]   (64x64 tiles)
//   [1792,2048) Wp [1024][1024] -> Wpt[n][d]=Wp[d][n]             (64x64 tiles)
//   [2048]      biases -> bqkv[3072]
// ---------------------------------------------------------------------------
__global__ __launch_bounds__(256) void prep2_kernel(
    const float* __restrict__ x,
    const float* __restrict__ Wk, const float* __restrict__ Wq,
    const float* __restrict__ Wv,
    const float* __restrict__ bk, const float* __restrict__ bq,
    const float* __restrict__ bv,
    const float* __restrict__ Wp,
    unsigned short* __restrict__ xb,
    unsigned short* __restrict__ Wt,
    unsigned short* __restrict__ Wpt,
    float* __restrict__ bqkv) {
  __shared__ float tile[64][65];              // +1 pad: conflict-free transpose
  const int bid = blockIdx.x, t = threadIdx.x;

  if (bid < 1024) {                           // ---- x cast ----
#pragma unroll
    for (int q = 0; q < 4; ++q) {
      int idx = bid * 1024 + q * 256 + t;     // 1M float4 total
      float4 v = ((const float4*)x)[idx];
      ushort4 o;
      o.x = f2bf(v.x); o.y = f2bf(v.y); o.z = f2bf(v.z); o.w = f2bf(v.w);
      ((ushort4*)xb)[idx] = o;
    }
  } else if (bid < 1792) {                    // ---- W k/q/v transpose ----
    int wb = bid - 1024;                      // [0,768)
    int p = wb >> 8, rem = wb & 255;          // p: 0=k 1=q 2=v
    int h = rem >> 4, dt = rem & 15;
    int d0 = dt * 64;
    const float* Wsrc = (p == 0) ? Wk : (p == 1) ? Wq : Wv;
    const float* src = Wsrc + ((size_t)h * 1024 + d0) * 64;   // rows d, cols e
#pragma unroll
    for (int q = 0; q < 16; ++q) {
      int idx = t + q * 256;
      int dr = idx >> 6, e = idx & 63;
      tile[dr][e] = src[(size_t)dr * 64 + e];                 // coalesced in e
    }
    __syncthreads();
    unsigned short* dst = Wt + ((size_t)p * 1024 + h * 64) * 1024 + d0;
#pragma unroll
    for (int q = 0; q < 16; ++q) {
      int idx = t + q * 256;
      int er = idx >> 6, dc = idx & 63;
      dst[(size_t)er * 1024 + dc] = f2bf(tile[dc][er]);       // coalesced in d
    }
  } else if (bid < 2048) {                    // ---- Wp transpose ----
    int wb = bid - 1792;                      // [0,256)
    int nt = wb >> 4, dt = wb & 15;
    int n0 = nt * 64, d0 = dt * 64;
#pragma unroll
    for (int q = 0; q < 16; ++q) {
      int idx = t + q * 256;
      int dr = idx >> 6, nc = idx & 63;
      tile[dr][nc] = Wp[(size_t)(d0 + dr) * 1024 + n0 + nc];  // coalesced in n
    }
    __syncthreads();
#pragma unroll
    for (int q = 0; q < 16; ++q) {
      int idx = t + q * 256;
      int er = idx >> 6, dc = idx & 63;
      Wpt[(size_t)(n0 + er) * 1024 + d0 + dc] = f2bf(tile[dc][er]);  // coalesced in d
    }
  } else {                                    // ---- biases ----
#pragma unroll
    for (int q = 0; q < 12; ++q) {
      int c = q * 256 + t;                    // [0,3072)
      int p = c >> 10;
      const float* bsrc = (p == 0) ? bk : (p == 1) ? bq : bv;
      bqkv[c] = bsrc[c & 1023];
    }
  }
}

// ---------------------------------------------------------------------------
// GEMM  C[M,N] = A[M,1024] * Bt[N,1024]^T  (both bf16, B stored transposed).
// 128x128 tile, BK=64, 4 waves (2x2 of 64x64), 16x16x32 bf16 MFMA.
// global_load_lds width-16 with pre-swizzled source (rule 21), XOR-swizzled reads.
// T1 bijective XCD swizzle (grid % 8 == 0 for both instantiations).
// MODE 0: QKV epilogue (bias add, scatter to K/Q [B,H,T,64] and V^T [B,H,64,T])
// MODE 1: fp32 out = acc + bias -> fout[M][1024]
// ---------------------------------------------------------------------------
template <int MODE>
__global__ __launch_bounds__(256, 2) void gemm_bt(
    const unsigned short* __restrict__ A,
    const unsigned short* __restrict__ Bt,
    const float* __restrict__ bias,
    unsigned short* __restrict__ kbuf,
    unsigned short* __restrict__ qbuf,
    unsigned short* __restrict__ vtbuf,
    float* __restrict__ fout,
    int gridN) {
  const int K = 1024;
  __shared__ __align__(16) unsigned short As[128 * 64];
  __shared__ __align__(16) unsigned short Bs[128 * 64];

  const int cpx = gridDim.x >> 3;             // grid % 8 == 0 guaranteed
  const int bid2 = (blockIdx.x & 7) * cpx + (blockIdx.x >> 3);   // XCD swizzle
  const int bm = bid2 / gridN, bn = bid2 % gridN;
  const int tid = threadIdx.x, wave = tid >> 6, lane = tid & 63;
  const int wm = wave >> 1, wn = wave & 1;
  const int l15 = lane & 15, l4 = lane >> 4;
  const long arow0 = (long)bm * 128;
  const long brow0 = (long)bn * 128;

  f32x4 acc[4][4];
  const f32x4 zf4 = {0.f, 0.f, 0.f, 0.f};
#pragma unroll
  for (int i = 0; i < 4; ++i)
#pragma unroll
    for (int j = 0; j < 4; ++j) acc[i][j] = zf4;

  for (int kt = 0; kt < 16; ++kt) {
#pragma unroll
    for (int s = 0; s < 4; ++s) {
      int ob = (wave * 4 + s) * 1024;         // wave-uniform LDS byte base
      int o = ob + lane * 16;
      int r = o >> 7;                          // tile row (128B rows)
      int cb = (o & 127) ^ ((r & 7) << 4);     // inverse-swizzled source column byte
      GLOAD_LDS16(A + (arow0 + r) * K + kt * 64 + (cb >> 1), (char*)As + ob);
      GLOAD_LDS16(Bt + (brow0 + r) * K + kt * 64 + (cb >> 1), (char*)Bs + ob);
    }
    __syncthreads();   // compiler drains vmcnt before s_barrier
#pragma unroll
    for (int kk = 0; kk < 2; ++kk) {
      s16x8 af[4], bfv[4];
#pragma unroll
      for (int i = 0; i < 4; ++i) {
        int row = wm * 64 + i * 16 + l15;
        int cb = (kk * 64 + l4 * 16) ^ ((row & 7) << 4);
        af[i] = *(const s16x8*)((const char*)As + row * 128 + cb);
      }
#pragma unroll
      for (int j = 0; j < 4; ++j) {
        int row = wn * 64 + j * 16 + l15;
        int cb = (kk * 64 + l4 * 16) ^ ((row & 7) << 4);
        bfv[j] = *(const s16x8*)((const char*)Bs + row * 128 + cb);
      }
#pragma unroll
      for (int i = 0; i < 4; ++i)
#pragma unroll
        for (int j = 0; j < 4; ++j)
          acc[i][j] = __builtin_amdgcn_mfma_f32_16x16x32_bf16(af[i], bfv[j], acc[i][j], 0, 0, 0);
    }
    __syncthreads();
  }

  const int gc0 = bn * 128;
  if (MODE == 0) {
    const int p = gc0 >> 10;                   // 0:k 1:q 2:v (uniform per block)
#pragma unroll
    for (int i = 0; i < 4; ++i) {
      int mrow = (int)arow0 + wm * 64 + i * 16 + l4 * 4;
      int b = mrow >> 10;
      int t = mrow & 1023;
#pragma unroll
      for (int j = 0; j < 4; ++j) {
        int gc = gc0 + wn * 64 + j * 16 + l15;
        int hc = gc & 1023;
        int hh = hc >> 6, e = hc & 63;
        float bb = bias[gc];
#pragma unroll
        for (int r = 0; r < 4; ++r) {
          unsigned short ub = f2bf(acc[i][j][r] + bb);
          if (p == 0)
            kbuf[(((long)(b * 16 + hh)) * 1024 + (t + r)) * 64 + e] = ub;
          else if (p == 1)
            qbuf[(((long)(b * 16 + hh)) * 1024 + (t + r)) * 64 + e] = ub;
          else
            vtbuf[(((long)(b * 16 + hh)) * 64 + e) * 1024 + (t + r)] = ub;
        }
      }
    }
  } else {
#pragma unroll
    for (int i = 0; i < 4; ++i) {
      long mrow = arow0 + wm * 64 + i * 16 + l4 * 4;
#pragma unroll
      for (int j = 0; j < 4; ++j) {
        int gc = gc0 + wn * 64 + j * 16 + l15;
        float bb = bias[gc];
#pragma unroll
        for (int r = 0; r < 4; ++r) fout[(mrow + r) * 1024 + gc] = acc[i][j][r] + bb;
      }
    }
  }
}

// ---------------------------------------------------------------------------
// Fused causal attention per (b,h, 128-row t-tile).
// scores = (K Q^T)/32  (faithful to reference: k@q^T), causal s<=t, softmax over s.
// Pass 1: exp-rowsums.  Pass 2: recompute QK^T, write normalized fp32 attn
// (zeros above diagonal), stage P->LDS bf16 (XOR swizzle), accumulate AV.
// K-frags hoisted to registers; Q,V from global (L2-resident, no staging).
// blockIdx.x pairing swizzle balances causal work: (0,7),(1,6),(2,5),(3,4).
// ---------------------------------------------------------------------------
__global__ __launch_bounds__(256, 2) void attn_fused(
    const unsigned short* __restrict__ Kb,
    const unsigned short* __restrict__ Qb,
    const unsigned short* __restrict__ Vt,
    float* __restrict__ attn,
    unsigned short* __restrict__ outh) {
  __shared__ __align__(16) unsigned short Ps[128 * 128];
  __shared__ float rsum[2][128];
  __shared__ float rinv[128];

  const int bh = blockIdx.y;
  const int bx = blockIdx.x;
  const int ttile = (bx & 1) ? (7 - (bx >> 1)) : (bx >> 1);  // work-pairing swizzle
  const int t0 = ttile * 128;
  const int b = bh >> 4, h = bh & 15;
  const unsigned short* Kbh = Kb + (long)bh * 65536;
  const unsigned short* Qbh = Qb + (long)bh * 65536;
  const unsigned short* Vbh = Vt + (long)bh * 65536;
  float* attn_bh = attn + (long)bh * 1048576;

  const int tid = threadIdx.x, wave = tid >> 6, lane = tid & 63;
  const int wm = wave >> 1, wn = wave & 1;
  const int l15 = lane & 15, l4 = lane >> 4;
  const f32x4 zf4 = {0.f, 0.f, 0.f, 0.f};

  // K fragments (A operand), rows t0 + wm*64 + i*16 + l15, k=e contiguous
  s16x8 kf[4][2];
#pragma unroll
  for (int i = 0; i < 4; ++i)
#pragma unroll
    for (int kk = 0; kk < 2; ++kk)
      kf[i][kk] = *(const s16x8*)(Kbh + (long)(t0 + wm * 64 + i * 16 + l15) * 64 + kk * 32 + l4 * 8);

  // ---- pass 1: per-row sum of exp ----
  float rs[4][4];
#pragma unroll
  for (int i = 0; i < 4; ++i)
#pragma unroll
    for (int r = 0; r < 4; ++r) rs[i][r] = 0.f;

  for (int st = 0; st <= ttile; ++st) {
    int s0 = st * 128;
    f32x4 acc[4][4];
#pragma unroll
    for (int i = 0; i < 4; ++i)
#pragma unroll
      for (int j = 0; j < 4; ++j) acc[i][j] = zf4;
#pragma unroll
    for (int kk = 0; kk < 2; ++kk) {
      s16x8 qf[4];
#pragma unroll
      for (int j = 0; j < 4; ++j)
        qf[j] = *(const s16x8*)(Qbh + (long)(s0 + wn * 64 + j * 16 + l15) * 64 + kk * 32 + l4 * 8);
#pragma unroll
      for (int i = 0; i < 4; ++i)
#pragma unroll
        for (int j = 0; j < 4; ++j)
          acc[i][j] = __builtin_amdgcn_mfma_f32_16x16x32_bf16(kf[i][kk], qf[j], acc[i][j], 0, 0, 0);
    }
    bool diag = (st == ttile);
#pragma unroll
    for (int i = 0; i < 4; ++i)
#pragma unroll
      for (int j = 0; j < 4; ++j)
#pragma unroll
        for (int r = 0; r < 4; ++r) {
          float sc = acc[i][j][r] * 0.03125f;
          if (diag) {
            int t = t0 + wm * 64 + i * 16 + l4 * 4 + r;
            int s = s0 + wn * 64 + j * 16 + l15;
            rs[i][r] += (s <= t) ? __expf(sc) : 0.f;
          } else {
            rs[i][r] += __expf(sc);
          }
        }
  }
  // reduce over the 16 s-lanes; cross-wave (wn) combine via LDS
#pragma unroll
  for (int i = 0; i < 4; ++i)
#pragma unroll
    for (int r = 0; r < 4; ++r) {
      float v = rs[i][r];
      v += __shfl_xor(v, 1);
      v += __shfl_xor(v, 2);
      v += __shfl_xor(v, 4);
      v += __shfl_xor(v, 8);
      if (l15 == 0) rsum[wn][wm * 64 + i * 16 + l4 * 4 + r] = v;
    }
  __syncthreads();
  if (tid < 128) rinv[tid] = 1.0f / (rsum[0][tid] + rsum[1][tid]);
  __syncthreads();

  float rinv_r[4][4];
#pragma unroll
  for (int i = 0; i < 4; ++i)
#pragma unroll
    for (int r = 0; r < 4; ++r) rinv_r[i][r] = rinv[wm * 64 + i * 16 + l4 * 4 + r];

  // ---- pass 2: attn store + AV ----
  f32x4 acc2[2][4];
#pragma unroll
  for (int i = 0; i < 2; ++i)
#pragma unroll
    for (int j = 0; j < 4; ++j) acc2[i][j] = zf4;

  for (int st = 0; st < 8; ++st) {
    int s0 = st * 128;
    if (st > ttile) {            // strictly above diagonal: exact zeros
      float4 z = make_float4(0.f, 0.f, 0.f, 0.f);
#pragma unroll
      for (int q = 0; q < 16; ++q) {
        int fi = tid + q * 256;
        int row = fi >> 5, c4 = fi & 31;
        *(float4*)(attn_bh + (long)(t0 + row) * 1024 + s0 + c4 * 4) = z;
      }
      continue;
    }
    f32x4 acc[4][4];
#pragma unroll
    for (int i = 0; i < 4; ++i)
#pragma unroll
      for (int j = 0; j < 4; ++j) acc[i][j] = zf4;
#pragma unroll
    for (int kk = 0; kk < 2; ++kk) {
      s16x8 qf[4];
#pragma unroll
      for (int j = 0; j < 4; ++j)
        qf[j] = *(const s16x8*)(Qbh + (long)(s0 + wn * 64 + j * 16 + l15) * 64 + kk * 32 + l4 * 8);
#pragma unroll
      for (int i = 0; i < 4; ++i)
#pragma unroll
        for (int j = 0; j < 4; ++j)
          acc[i][j] = __builtin_amdgcn_mfma_f32_16x16x32_bf16(kf[i][kk], qf[j], acc[i][j], 0, 0, 0);
    }
    bool diag = (st == ttile);
#pragma unroll
    for (int i = 0; i < 4; ++i) {
      int tl = wm * 64 + i * 16 + l4 * 4;
#pragma unroll
      for (int j = 0; j < 4; ++j) {
        int sl = wn * 64 + j * 16 + l15;
#pragma unroll
        for (int r = 0; r < 4; ++r) {
          int t = t0 + tl + r;
          int s = s0 + sl;
          float p = (!diag || s <= t) ? __expf(acc[i][j][r] * 0.03125f) * rinv_r[i][r] : 0.f;
          attn_bh[(long)t * 1024 + s] = p;
          int lt = tl + r;
          Ps[lt * 128 + (sl ^ ((lt & 15) << 3))] = f2bf(p);   // element swz, 16B gran
        }
      }
    }
    __syncthreads();
    // AV: wave owns 32 t-rows; P from swizzled LDS (A), V^T from global (B)
#pragma unroll
    for (int kk2 = 0; kk2 < 4; ++kk2) {
      s16x8 pf[2];
#pragma unroll
      for (int i2 = 0; i2 < 2; ++i2) {
        int lt = wave * 32 + i2 * 16 + l15;
        int ls = kk2 * 32 + l4 * 8;
        pf[i2] = *(const s16x8*)&Ps[lt * 128 + (ls ^ ((lt & 15) << 3))];
      }
      s16x8 vf[4];
#pragma unroll
      for (int j2 = 0; j2 < 4; ++j2)
        vf[j2] = *(const s16x8*)(Vbh + (long)(j2 * 16 + l15) * 1024 + s0 + kk2 * 32 + l4 * 8);
#pragma unroll
      for (int i2 = 0; i2 < 2; ++i2)
#pragma unroll
        for (int j2 = 0; j2 < 4; ++j2)
          acc2[i2][j2] = __builtin_amdgcn_mfma_f32_16x16x32_bf16(pf[i2], vf[j2], acc2[i2][j2], 0, 0, 0);
    }
    __syncthreads();
  }

  // outh[b*1024+t][h*64+e] bf16, ready as A for the final GEMM
#pragma unroll
  for (int i2 = 0; i2 < 2; ++i2)
#pragma unroll
    for (int j2 = 0; j2 < 4; ++j2)
#pragma unroll
      for (int r = 0; r < 4; ++r) {
        int t = t0 + wave * 32 + i2 * 16 + l4 * 4 + r;
        int e = j2 * 16 + l15;
        outh[(long)(b * 1024 + t) * 1024 + h * 64 + e] = f2bf(acc2[i2][j2][r]);
      }
}

// ---------------------------------------------------------------------------
extern "C" void kernel_launch(void* const* d_in, const int* in_sizes, int n_in,
                              void* d_out, int out_size, void* d_ws, size_t ws_size,
                              hipStream_t stream) {
  const float* x  = (const float*)d_in[0];
  const float* Wk = (const float*)d_in[1];
  const float* bk = (const float*)d_in[2];
  const float* Wq = (const float*)d_in[3];
  const float* bq = (const float*)d_in[4];
  const float* Wv = (const float*)d_in[5];
  const float* bv = (const float*)d_in[6];
  const float* Wp = (const float*)d_in[7];
  const float* bp = (const float*)d_in[8];

  char* ws = (char*)d_ws;
  unsigned short* xb   = (unsigned short*)(ws);              // 8,388,608 B
  unsigned short* Wt   = (unsigned short*)(ws + 8388608);    // 6,291,456 B
  unsigned short* Wpt  = (unsigned short*)(ws + 14680064);   // 2,097,152 B
  float*          bqkv = (float*)(ws + 16777216);            //    12,288 B
  unsigned short* Kbuf = (unsigned short*)(ws + 16789504);   // 8,388,608 B
  unsigned short* Qbuf = (unsigned short*)(ws + 25178112);   // 8,388,608 B
  unsigned short* Vtb  = (unsigned short*)(ws + 33566720);   // 8,388,608 B
  unsigned short* outh = (unsigned short*)(ws + 41955328);   // 8,388,608 B -> 50,343,936 total

  float* out  = (float*)d_out;
  float* attn = out + 4194304;

  prep2_kernel<<<dim3(2049), dim3(256), 0, stream>>>(x, Wk, Wq, Wv, bk, bq, bv, Wp,
                                                     xb, Wt, Wpt, bqkv);
  gemm_bt<0><<<dim3(768), dim3(256), 0, stream>>>(xb, Wt, bqkv, Kbuf, Qbuf, Vtb,
                                                  (float*)nullptr, 24);
  attn_fused<<<dim3(8, 64), dim3(256), 0, stream>>>(Kbuf, Qbuf, Vtb, attn, outh);
  gemm_bt<1><<<dim3(256), dim3(256), 0, stream>>>(outh, Wpt, bp,
                                                  (unsigned short*)nullptr,
                                                  (unsigned short*)nullptr,
                                                  (unsigned short*)nullptr, out, 8);
}

// Round 11
// 443.720 us; speedup vs baseline: 1.1961x; 1.1571x over previous
//
#include <hip/hip_runtime.h>
#include <hip/hip_bf16.h>
#include <stdint.h>

// MultiHeadAttention fused forward, MI355X gfx950.
// B=4 T=1024 D=1024 H=16 HS=64.  All math bf16-MFMA with fp32 accum.

using f32x4 = __attribute__((ext_vector_type(4))) float;
using s16x8 = __attribute__((ext_vector_type(8))) short;   // 8 bf16 = 4 VGPR

#define GLOAD_LDS16(g, l)                                                          \
  __builtin_amdgcn_global_load_lds((const __attribute__((address_space(1))) void*)(g), \
                                   (__attribute__((address_space(3))) void*)(l), 16, 0, 0)

__device__ __forceinline__ unsigned short f2bf(float f) {
  unsigned u = __float_as_uint(f);
  u = (u + 0x7FFFu + ((u >> 16) & 1u)) >> 16;   // RNE
  return (unsigned short)u;
}
__device__ __forceinline__ float bf2f(unsigned short u) {
  return __uint_as_float(((unsigned)u) << 16);
}

// ---------------------------------------------------------------------------
// prep2: block-range dispatch, all transposes LDS-tiled (coalesced both sides).
// ---------------------------------------------------------------------------
__global__ __launch_bounds__(256) void prep2_kernel(
    const float* __restrict__ x,
    const float* __restrict__ Wk, const float* __restrict__ Wq,
    const float* __restrict__ Wv,
    const float* __restrict__ bk, const float* __restrict__ bq,
    const float* __restrict__ bv,
    const float* __restrict__ Wp,
    unsigned short* __restrict__ xb,
    unsigned short* __restrict__ Wt,
    unsigned short* __restrict__ Wpt,
    float* __restrict__ bqkv) {
  __shared__ float tile[64][65];
  const int bid = blockIdx.x, t = threadIdx.x;

  if (bid < 1024) {                           // ---- x cast ----
#pragma unroll
    for (int q = 0; q < 4; ++q) {
      int idx = bid * 1024 + q * 256 + t;
      float4 v = ((const float4*)x)[idx];
      ushort4 o;
      o.x = f2bf(v.x); o.y = f2bf(v.y); o.z = f2bf(v.z); o.w = f2bf(v.w);
      ((ushort4*)xb)[idx] = o;
    }
  } else if (bid < 1792) {                    // ---- W k/q/v transpose ----
    int wb = bid - 1024;
    int p = wb >> 8, rem = wb & 255;
    int h = rem >> 4, dt = rem & 15;
    int d0 = dt * 64;
    const float* Wsrc = (p == 0) ? Wk : (p == 1) ? Wq : Wv;
    const float* src = Wsrc + ((size_t)h * 1024 + d0) * 64;
#pragma unroll
    for (int q = 0; q < 16; ++q) {
      int idx = t + q * 256;
      int dr = idx >> 6, e = idx & 63;
      tile[dr][e] = src[(size_t)dr * 64 + e];
    }
    __syncthreads();
    unsigned short* dst = Wt + ((size_t)p * 1024 + h * 64) * 1024 + d0;
#pragma unroll
    for (int q = 0; q < 16; ++q) {
      int idx = t + q * 256;
      int er = idx >> 6, dc = idx & 63;
      dst[(size_t)er * 1024 + dc] = f2bf(tile[dc][er]);
    }
  } else if (bid < 2048) {                    // ---- Wp transpose ----
    int wb = bid - 1792;
    int nt = wb >> 4, dt = wb & 15;
    int n0 = nt * 64, d0 = dt * 64;
#pragma unroll
    for (int q = 0; q < 16; ++q) {
      int idx = t + q * 256;
      int dr = idx >> 6, nc = idx & 63;
      tile[dr][nc] = Wp[(size_t)(d0 + dr) * 1024 + n0 + nc];
    }
    __syncthreads();
#pragma unroll
    for (int q = 0; q < 16; ++q) {
      int idx = t + q * 256;
      int er = idx >> 6, dc = idx & 63;
      Wpt[(size_t)(n0 + er) * 1024 + d0 + dc] = f2bf(tile[dc][er]);
    }
  } else {                                    // ---- biases ----
#pragma unroll
    for (int q = 0; q < 12; ++q) {
      int c = q * 256 + t;
      int p = c >> 10;
      const float* bsrc = (p == 0) ? bk : (p == 1) ? bq : bv;
      bqkv[c] = bsrc[c & 1023];
    }
  }
}

// ---------------------------------------------------------------------------
// GEMM  C[M,N] = A[M,1024] * Bt[N,1024]^T.  128x128 tile, BK=64, 4 waves,
// global_load_lds w16 + XOR swizzle, XCD swizzle.
// MODE 0: QKV epilogue.  V^T blocks use an LDS-bounce transpose (coalesced
// 16B stores) instead of the 2B/2KB-stride scatter.
// MODE 1: fp32 out = acc + bias.
// ---------------------------------------------------------------------------
template <int MODE>
__global__ __launch_bounds__(256, 2) void gemm_bt(
    const unsigned short* __restrict__ A,
    const unsigned short* __restrict__ Bt,
    const float* __restrict__ bias,
    unsigned short* __restrict__ kbuf,
    unsigned short* __restrict__ qbuf,
    unsigned short* __restrict__ vtbuf,
    float* __restrict__ fout,
    int gridN) {
  const int K = 1024;
  __shared__ __align__(16) unsigned short Sh[128 * 128];   // 32 KB: staging + bounce
  unsigned short* As = Sh;
  unsigned short* Bs = Sh + 8192;

  const int cpx = gridDim.x >> 3;
  const int bid2 = (blockIdx.x & 7) * cpx + (blockIdx.x >> 3);   // XCD swizzle
  const int bm = bid2 / gridN, bn = bid2 % gridN;
  const int tid = threadIdx.x, wave = tid >> 6, lane = tid & 63;
  const int wm = wave >> 1, wn = wave & 1;
  const int l15 = lane & 15, l4 = lane >> 4;
  const long arow0 = (long)bm * 128;
  const long brow0 = (long)bn * 128;

  f32x4 acc[4][4];
  const f32x4 zf4 = {0.f, 0.f, 0.f, 0.f};
#pragma unroll
  for (int i = 0; i < 4; ++i)
#pragma unroll
    for (int j = 0; j < 4; ++j) acc[i][j] = zf4;

  for (int kt = 0; kt < 16; ++kt) {
#pragma unroll
    for (int s = 0; s < 4; ++s) {
      int ob = (wave * 4 + s) * 1024;
      int o = ob + lane * 16;
      int r = o >> 7;
      int cb = (o & 127) ^ ((r & 7) << 4);
      GLOAD_LDS16(A + (arow0 + r) * K + kt * 64 + (cb >> 1), (char*)As + ob);
      GLOAD_LDS16(Bt + (brow0 + r) * K + kt * 64 + (cb >> 1), (char*)Bs + ob);
    }
    __syncthreads();
#pragma unroll
    for (int kk = 0; kk < 2; ++kk) {
      s16x8 af[4], bfv[4];
#pragma unroll
      for (int i = 0; i < 4; ++i) {
        int row = wm * 64 + i * 16 + l15;
        int cb = (kk * 64 + l4 * 16) ^ ((row & 7) << 4);
        af[i] = *(const s16x8*)((const char*)As + row * 128 + cb);
      }
#pragma unroll
      for (int j = 0; j < 4; ++j) {
        int row = wn * 64 + j * 16 + l15;
        int cb = (kk * 64 + l4 * 16) ^ ((row & 7) << 4);
        bfv[j] = *(const s16x8*)((const char*)Bs + row * 128 + cb);
      }
#pragma unroll
      for (int i = 0; i < 4; ++i)
#pragma unroll
        for (int j = 0; j < 4; ++j)
          acc[i][j] = __builtin_amdgcn_mfma_f32_16x16x32_bf16(af[i], bfv[j], acc[i][j], 0, 0, 0);
    }
    __syncthreads();
  }

  const int gc0 = bn * 128;
  if (MODE == 0) {
    const int p = gc0 >> 10;                   // 0:k 1:q 2:v (block-uniform)
    if (p == 2) {
      // ---- V^T via LDS bounce: stage C^T (bias-added, bf16) swizzled ----
#pragma unroll
      for (int i = 0; i < 4; ++i) {
        int tl = wm * 64 + i * 16 + l4 * 4;
#pragma unroll
        for (int j = 0; j < 4; ++j) {
          int el = wn * 64 + j * 16 + l15;
          float bb = bias[gc0 + el];
#pragma unroll
          for (int r = 0; r < 4; ++r) {
            unsigned short ub = f2bf(acc[i][j][r] + bb);
            *(unsigned short*)((char*)Sh + el * 256 + (((tl + r) * 2) ^ ((el & 15) << 4))) = ub;
          }
        }
      }
      __syncthreads();
      const int b = (int)(arow0 >> 10);
      const int hhb = (gc0 & 1023) >> 6;
      const int tcb = (int)(arow0 & 1023);
      int el = tid >> 1, ch = tid & 1;
      long vrow = ((long)(b * 16 + hhb + (el >> 6))) * 64 + (el & 63);
#pragma unroll
      for (int c8 = 0; c8 < 8; ++c8) {
        s16x8 u = *(const s16x8*)((const char*)Sh + el * 256 + ((ch * 128 + c8 * 16) ^ ((el & 15) << 4)));
        *(s16x8*)(vtbuf + vrow * 1024 + tcb + ch * 64 + c8 * 8) = u;
      }
    } else {
#pragma unroll
      for (int i = 0; i < 4; ++i) {
        int mrow = (int)arow0 + wm * 64 + i * 16 + l4 * 4;
        int b = mrow >> 10;
        int t = mrow & 1023;
#pragma unroll
        for (int j = 0; j < 4; ++j) {
          int gc = gc0 + wn * 64 + j * 16 + l15;
          int hc = gc & 1023;
          int hh = hc >> 6, e = hc & 63;
          float bb = bias[gc];
#pragma unroll
          for (int r = 0; r < 4; ++r) {
            unsigned short ub = f2bf(acc[i][j][r] + bb);
            if (p == 0)
              kbuf[(((long)(b * 16 + hh)) * 1024 + (t + r)) * 64 + e] = ub;
            else
              qbuf[(((long)(b * 16 + hh)) * 1024 + (t + r)) * 64 + e] = ub;
          }
        }
      }
    }
  } else {
#pragma unroll
    for (int i = 0; i < 4; ++i) {
      long mrow = arow0 + wm * 64 + i * 16 + l4 * 4;
#pragma unroll
      for (int j = 0; j < 4; ++j) {
        int gc = gc0 + wn * 64 + j * 16 + l15;
        float bb = bias[gc];
#pragma unroll
        for (int r = 0; r < 4; ++r) fout[(mrow + r) * 1024 + gc] = acc[i][j][r] + bb;
      }
    }
  }
}

// ---------------------------------------------------------------------------
// Fused causal attention, SINGLE-PASS: per (b,h, 32-row t-strip).
// Phase 1: QK^T once; masked bf16 P -> LDS (XOR-swizzled [32][1024]);
//          rowsums accumulated from the bf16-rounded values (self-consistent).
// Phase 2a: attn = P * (1/L), fully-vectorized float4 stores, zeros beyond diag.
// Phase 2b: AV with unnormalized P from LDS; scale O by 1/L at the end.
// 3 barriers/block total.  Causal pairing over 32 t-strips (pair sum = 9 tiles).
// ---------------------------------------------------------------------------
__global__ __launch_bounds__(256, 2) void attn_fused2(
    const unsigned short* __restrict__ Kb,
    const unsigned short* __restrict__ Qb,
    const unsigned short* __restrict__ Vt,
    float* __restrict__ attn,
    unsigned short* __restrict__ outh) {
  __shared__ __align__(16) unsigned short Pl[32 * 1024];   // 64 KB, swizzled
  __shared__ float rsum[4][32];
  __shared__ float rinv[32];

  const int bh = blockIdx.y;
  const int bx = blockIdx.x;
  const int ttile = (bx & 1) ? (31 - (bx >> 1)) : (bx >> 1);   // pairing swizzle
  const int t0 = ttile * 32;
  const int st_lim = ttile >> 2;                // inclusive diagonal s-tile
  const int b = bh >> 4, h = bh & 15;
  const unsigned short* Kbh = Kb + (long)bh * 65536;
  const unsigned short* Qbh = Qb + (long)bh * 65536;
  const unsigned short* Vbh = Vt + (long)bh * 65536;
  float* attn_bh = attn + (long)bh * 1048576;

  const int tid = threadIdx.x, w = tid >> 6, lane = tid & 63;
  const int l15 = lane & 15, l4 = lane >> 4;
  const f32x4 zf4 = {0.f, 0.f, 0.f, 0.f};

  // K fragments: rows t0 + i*16 + l15 (i=0..1), k=e contiguous
  s16x8 kf[2][2];
#pragma unroll
  for (int i = 0; i < 2; ++i)
#pragma unroll
    for (int kk = 0; kk < 2; ++kk)
      kf[i][kk] = *(const s16x8*)(Kbh + (long)(t0 + i * 16 + l15) * 64 + kk * 32 + l4 * 8);

  // ---- phase 1: QK^T once, P->LDS (masked bf16), rowsums ----
  float rs[2][4];
#pragma unroll
  for (int i = 0; i < 2; ++i)
#pragma unroll
    for (int r = 0; r < 4; ++r) rs[i][r] = 0.f;

  for (int st = 0; st <= st_lim; ++st) {
    int s0 = st * 128;
    f32x4 acc[2][2];
#pragma unroll
    for (int i = 0; i < 2; ++i)
#pragma unroll
      for (int j = 0; j < 2; ++j) acc[i][j] = zf4;
#pragma unroll
    for (int kk = 0; kk < 2; ++kk) {
      s16x8 qf[2];
#pragma unroll
      for (int j = 0; j < 2; ++j)
        qf[j] = *(const s16x8*)(Qbh + (long)(s0 + w * 32 + j * 16 + l15) * 64 + kk * 32 + l4 * 8);
#pragma unroll
      for (int i = 0; i < 2; ++i)
#pragma unroll
        for (int j = 0; j < 2; ++j)
          acc[i][j] = __builtin_amdgcn_mfma_f32_16x16x32_bf16(kf[i][kk], qf[j], acc[i][j], 0, 0, 0);
    }
    bool diag = (st == st_lim);
#pragma unroll
    for (int i = 0; i < 2; ++i)
#pragma unroll
      for (int j = 0; j < 2; ++j) {
        int s = s0 + w * 32 + j * 16 + l15;
#pragma unroll
        for (int r = 0; r < 4; ++r) {
          int tl = i * 16 + l4 * 4 + r;
          float e = __expf(acc[i][j][r] * 0.03125f);
          unsigned short ub = (!diag || s <= t0 + tl) ? f2bf(e) : (unsigned short)0;
          rs[i][r] += bf2f(ub);
          *(unsigned short*)((char*)Pl + tl * 2048 + ((s * 2) ^ ((tl & 7) << 4))) = ub;
        }
      }
  }
  // rowsum: 16-lane shuffle reduce + cross-wave via LDS
#pragma unroll
  for (int i = 0; i < 2; ++i)
#pragma unroll
    for (int r = 0; r < 4; ++r) {
      float v = rs[i][r];
      v += __shfl_xor(v, 1);
      v += __shfl_xor(v, 2);
      v += __shfl_xor(v, 4);
      v += __shfl_xor(v, 8);
      if (l15 == 0) rsum[w][i * 16 + l4 * 4 + r] = v;
    }
  __syncthreads();
  if (tid < 32) rinv[tid] = 1.0f / (rsum[0][tid] + rsum[1][tid] + rsum[2][tid] + rsum[3][tid]);
  __syncthreads();

  // ---- phase 2a: attn store, fully coalesced float4 ----
  {
    int row = tid >> 3, cb = tid & 7;         // 8 threads per row
    int tg = t0 + row;
    float ri = rinv[row];
#pragma unroll
    for (int g = 0; g < 16; ++g) {            // cols g*64 + cb*8 .. +7
      int c0 = g * 64 + cb * 8;
      float4 o0, o1;
      if ((g >> 1) <= st_lim) {
        s16x8 u = *(const s16x8*)((const char*)Pl + row * 2048 + ((c0 * 2) ^ ((row & 7) << 4)));
        o0.x = bf2f((unsigned short)u[0]) * ri;
        o0.y = bf2f((unsigned short)u[1]) * ri;
        o0.z = bf2f((unsigned short)u[2]) * ri;
        o0.w = bf2f((unsigned short)u[3]) * ri;
        o1.x = bf2f((unsigned short)u[4]) * ri;
        o1.y = bf2f((unsigned short)u[5]) * ri;
        o1.z = bf2f((unsigned short)u[6]) * ri;
        o1.w = bf2f((unsigned short)u[7]) * ri;
      } else {
        o0 = make_float4(0.f, 0.f, 0.f, 0.f);
        o1 = o0;
      }
      *(float4*)(attn_bh + (long)tg * 1024 + c0) = o0;
      *(float4*)(attn_bh + (long)tg * 1024 + c0 + 4) = o1;
    }
  }

  // ---- phase 2b: AV from LDS P (unnormalized), scale at end ----
  f32x4 acc2[2];
  acc2[0] = zf4; acc2[1] = zf4;
  const int i2 = w & 1, eh = (w >> 1) * 32;
  for (int st = 0; st <= st_lim; ++st) {
    int s0 = st * 128;
#pragma unroll
    for (int kk2 = 0; kk2 < 4; ++kk2) {
      int tl = i2 * 16 + l15;
      int k = s0 + kk2 * 32 + l4 * 8;
      s16x8 pf = *(const s16x8*)((const char*)Pl + tl * 2048 + ((k * 2) ^ ((tl & 7) << 4)));
#pragma unroll
      for (int j2 = 0; j2 < 2; ++j2) {
        s16x8 vf = *(const s16x8*)(Vbh + (long)(eh + j2 * 16 + l15) * 1024 + k);
        acc2[j2] = __builtin_amdgcn_mfma_f32_16x16x32_bf16(pf, vf, acc2[j2], 0, 0, 0);
      }
    }
  }
#pragma unroll
  for (int j2 = 0; j2 < 2; ++j2)
#pragma unroll
    for (int r = 0; r < 4; ++r) {
      int tl = i2 * 16 + l4 * 4 + r;
      int e = eh + j2 * 16 + l15;
      float o = acc2[j2][r] * rinv[tl];
      outh[(long)(b * 1024 + t0 + tl) * 1024 + h * 64 + e] = f2bf(o);
    }
}

// ---------------------------------------------------------------------------
extern "C" void kernel_launch(void* const* d_in, const int* in_sizes, int n_in,
                              void* d_out, int out_size, void* d_ws, size_t ws_size,
                              hipStream_t stream) {
  const float* x  = (const float*)d_in[0];
  const float* Wk = (const float*)d_in[1];
  const float* bk = (const float*)d_in[2];
  const float* Wq = (const float*)d_in[3];
  const float* bq = (const float*)d_in[4];
  const float* Wv = (const float*)d_in[5];
  const float* bv = (const float*)d_in[6];
  const float* Wp = (const float*)d_in[7];
  const float* bp = (const float*)d_in[8];

  char* ws = (char*)d_ws;
  unsigned short* xb   = (unsigned short*)(ws);              // 8,388,608 B
  unsigned short* Wt   = (unsigned short*)(ws + 8388608);    // 6,291,456 B
  unsigned short* Wpt  = (unsigned short*)(ws + 14680064);   // 2,097,152 B
  float*          bqkv = (float*)(ws + 16777216);            //    12,288 B
  unsigned short* Kbuf = (unsigned short*)(ws + 16789504);   // 8,388,608 B
  unsigned short* Qbuf = (unsigned short*)(ws + 25178112);   // 8,388,608 B
  unsigned short* Vtb  = (unsigned short*)(ws + 33566720);   // 8,388,608 B
  unsigned short* outh = (unsigned short*)(ws + 41955328);   // 8,388,608 B

  float* out  = (float*)d_out;
  float* attn = out + 4194304;

  prep2_kernel<<<dim3(2049), dim3(256), 0, stream>>>(x, Wk, Wq, Wv, bk, bq, bv, Wp,
                                                     xb, Wt, Wpt, bqkv);
  gemm_bt<0><<<dim3(768), dim3(256), 0, stream>>>(xb, Wt, bqkv, Kbuf, Qbuf, Vtb,
                                                  (float*)nullptr, 24);
  attn_fused2<<<dim3(32, 64), dim3(256), 0, stream>>>(Kbuf, Qbuf, Vtb, attn, outh);
  gemm_bt<1><<<dim3(256), dim3(256), 0, stream>>>(outh, Wpt, bp,
                                                  (unsigned short*)nullptr,
                                                  (unsigned short*)nullptr,
                                                  (unsigned short*)nullptr, out, 8);
}